// Round 1
// 454.363 us; speedup vs baseline: 1.2188x; 1.2188x over previous
//
#include <hip/hip_runtime.h>

// VoxelToPoint via fixed-capacity bucketing + per-line-group LDS gather.
//
// R3 used counting sort (zero -> hist -> scan -> scatter -> gather). The
// single-1024-thread-block scan serializes 2x65536 stride-256B accesses on
// ONE CU (every wave load fans out to 64 distinct 64B lines, mostly L2-miss
// after cross-XCD atomics) -- estimated 300-400 us of the 553 us total.
// R4: drop hist+scan. Scatter appends into fixed-capacity (CAP=32) buckets
// with atomicAdd; expected occupancy is Poisson(6.1) per 16-voxel line
// group, so overflow is ~impossible -- but any overflow point is appended
// to an atomic list and fixed up by a tiny direct-gather kernel (normally
// reads 0 and exits). Pipeline: zero(260KB) -> scatter -> gather3 -> ovf.
//
// gather3: one workgroup per line-group loads its 16 voxels x 64 channels
// (4KB) into LDS once with float4 (4 lanes/line), then the ~6 points
// sharing the group read LDS and write coalesced 256B per point.

#define DDIM 64
#define HDIM 64
#define WDIM 64
#define CCH 64
#define DHW (DDIM * HDIM * WDIM)          // 1<<18
#define GROUPS_PER_B 16384                 // DHW/16: one 64B line-group per 16 z-voxels
#define NGROUPS_SHIFT 14
#define CAP 32                             // bucket capacity; Poisson(6.1), P(>32)~1e-15
#define LDS_STRIDE 17                      // 16 + 1 pad: odd stride -> 2-way bank alias (free)

__global__ void zero_kernel(int* __restrict__ p, int n) {
  int i = blockIdx.x * blockDim.x + threadIdx.x;
  if (i < n) p[i] = 0;
}

__device__ __forceinline__ void decode_point(const int* cp, bool& valid, int& idx) {
  int x = cp[0], y = cp[1], z = cp[2];
  valid = (x < DDIM) && (y < HDIM) && (z < WDIM);  // reference: upper bound only
  int xi = min(max(x, 0), DDIM - 1);
  int yi = min(max(y, 0), HDIM - 1);
  int zi = min(max(z, 0), WDIM - 1);
  idx = (xi * HDIM + yi) * WDIM + zi;
}

// records[g*CAP + pos] = pid | zoff<<19 | invalid<<23   (pid < 2^19)
__global__ void scatter_kernel(const int* __restrict__ coords, int* __restrict__ counts,
                               int* __restrict__ records, int* __restrict__ ovf_count,
                               int* __restrict__ ovf_list, int B, int N) {
  int p = blockIdx.x * blockDim.x + threadIdx.x;
  if (p >= B * N) return;
  int b = p / N;
  bool valid; int idx;
  decode_point(coords + (size_t)p * 3, valid, idx);
  int g = b * GROUPS_PER_B + (idx >> 4);
  int pos = atomicAdd(&counts[g], 1);
  if (pos < CAP) {
    records[g * CAP + pos] = p | ((idx & 15) << 19) | (valid ? 0 : (1 << 23));
  } else {
    int o = atomicAdd(ovf_count, 1);   // astronomically rare; correctness net
    ovf_list[o] = p;
  }
}

// One workgroup per (b, line-group). counts[g] gives bucket size directly.
__global__ __launch_bounds__(256) void gather3_kernel(
    const float* __restrict__ vf, const int* __restrict__ counts,
    const int* __restrict__ records, float* __restrict__ out) {
  __shared__ float lds[CCH * LDS_STRIDE];
  int g = blockIdx.x;
  int cnt = counts[g];
  if (cnt == 0) return;  // uniform: whole block exits before barrier
  cnt = min(cnt, CAP);
  int b = g >> NGROUPS_SHIFT;
  int group = g & (GROUPS_PER_B - 1);
  int t = threadIdx.x;

  // Stage 4KB: 64 channels x 16 floats. ch = t>>2, 16B chunk = t&3.
  {
    int ch = t >> 2;
    int sub = t & 3;
    const float* src = vf + ((size_t)(b * CCH + ch) << 18) + (group << 4) + (sub << 2);
    float4 v4 = *(const float4*)src;
    float* dst = &lds[ch * LDS_STRIDE + (sub << 2)];
    dst[0] = v4.x; dst[1] = v4.y; dst[2] = v4.z; dst[3] = v4.w;
  }
  __syncthreads();

  int ch = t & 63;
  const int* rb = records + g * CAP;
  for (int s = (t >> 6); s < cnt; s += 4) {
    int r = rb[s];                   // 64 lanes same addr -> broadcast
    int pid = r & 0x7FFFF;
    int zoff = (r >> 19) & 15;
    float v = (r & (1 << 23)) ? 0.0f : lds[ch * LDS_STRIDE + zoff];
    // out never re-read by us; nt store keeps L2 for records/counts
    __builtin_nontemporal_store(v, &out[((size_t)pid << 6) + ch]);
  }
}

// Cleanup for bucket-overflow points (normally n==0: load one int, exit).
__global__ __launch_bounds__(256) void ovf_kernel(
    const float* __restrict__ vf, const int* __restrict__ coords,
    const int* __restrict__ ovf_count, const int* __restrict__ ovf_list,
    float* __restrict__ out, int N) {
  int n = *ovf_count;
  if (n == 0) return;
  int w = (blockIdx.x * blockDim.x + threadIdx.x) >> 6;
  int lane = threadIdx.x & 63;
  int nw = (gridDim.x * blockDim.x) >> 6;
  for (int i = w; i < n; i += nw) {
    int p = ovf_list[i];
    int b = p / N;
    bool valid; int idx;
    decode_point(coords + (size_t)p * 3, valid, idx);
    float v = valid ? vf[((size_t)(b * CCH + lane) << 18) + idx] : 0.0f;
    out[((size_t)p << 6) + lane] = v;
  }
}

// Fallback if workspace too small.
__global__ __launch_bounds__(256) void direct_kernel(const float* __restrict__ vf,
                                                     const int* __restrict__ coords,
                                                     float* __restrict__ out,
                                                     int B, int N) {
  int gid = blockIdx.x * blockDim.x + threadIdx.x;
  int point = gid >> 6;
  int lane = gid & 63;
  if (point >= B * N) return;
  int b = point / N;
  bool valid; int idx;
  decode_point(coords + (size_t)point * 3, valid, idx);
  float v = 0.0f;
  if (valid) v = vf[(size_t)(b * CCH + lane) * DHW + idx];
  out[(size_t)point * CCH + lane] = v;
}

extern "C" void kernel_launch(void* const* d_in, const int* in_sizes, int n_in,
                              void* d_out, int out_size, void* d_ws, size_t ws_size,
                              hipStream_t stream) {
  const float* vf = (const float*)d_in[0];
  const int* coords = (const int*)d_in[1];
  float* out = (float*)d_out;

  int B = in_sizes[0] / (CCH * DHW);  // 4
  int N = in_sizes[1] / (B * 3);      // 100000
  int total = B * N;

  int nbuckets = B * GROUPS_PER_B;                    // 65536
  size_t counts_ints = (size_t)nbuckets + 64;         // counts + ovf counter pad
  size_t rec_ints = (size_t)nbuckets * CAP;           // 2M ints = 8 MB
  size_t need = (counts_ints + rec_ints + (size_t)total) * sizeof(int);  // ~10.3 MB

  if (ws_size < need || total >= (1 << 19)) {
    int threads = total * 64;
    direct_kernel<<<(threads + 255) / 256, 256, 0, stream>>>(vf, coords, out, B, N);
    return;
  }

  int* counts = (int*)d_ws;
  int* ovf_count = counts + nbuckets;
  int* records = counts + counts_ints;
  int* ovf_list = records + rec_ints;

  zero_kernel<<<((int)counts_ints + 255) / 256, 256, 0, stream>>>(counts, (int)counts_ints);
  scatter_kernel<<<(total + 255) / 256, 256, 0, stream>>>(coords, counts, records,
                                                          ovf_count, ovf_list, B, N);
  gather3_kernel<<<nbuckets, 256, 0, stream>>>(vf, counts, records, out);
  ovf_kernel<<<32, 256, 0, stream>>>(vf, coords, ovf_count, ovf_list, out, N);
}

// Round 3
// 407.721 us; speedup vs baseline: 1.3582x; 1.1144x over previous
//
#include <hip/hip_runtime.h>

// VoxelToPoint via fixed-capacity bucketing + multi-group LDS gather.
//
// R4 post-mortem: scan removal saved only ~100us; remaining dominant kernel
// is the gather (~150us), which is latency-bound (per-block dependent chain:
// counts load -> stage -> barrier -> per-iter global records load) and
// fetch-split-bound (64B channel rows; adjacent groups sharing a 128B L2
// line land on different XCDs -> ~2x vf over-fetch).
// R5 (gather4): one block handles G=8 CONSECUTIVE groups.
//  - 512B contiguous per channel row: each 128B line belongs to one block
//    -> compulsory-only vf fetch, 8x MLP (8 independent float4s/thread).
//  - records for the 8 groups are 1KB contiguous -> prefetched to LDS as
//    int4; read loop is LDS-only (no dependent global broadcast chain).
//  - no early-exit counts check (P(all 8 empty) ~ 0) -> no serial stall.
//  - nontemporal vf loads: lines are read exactly once, keep L2 for records.
//  - R6 fix: __builtin_nontemporal_load needs a clang ext_vector_type, not
//    HIP's float4 class -> load via f32x4.
// Pipeline: zero(260KB) -> scatter -> gather4 -> ovf.

#define DDIM 64
#define HDIM 64
#define WDIM 64
#define CCH 64
#define DHW (DDIM * HDIM * WDIM)          // 1<<18
#define GROUPS_PER_B 16384                 // DHW/16: one 64B line-group per 16 z-voxels
#define NGROUPS_SHIFT 14
#define CAP 32                             // bucket capacity; Poisson(6.1), P(>32)~1e-15
#define GRP 8                              // groups per gather block
#define ROWLEN (GRP * 16 + 17)             // 145 floats: 145%32=17 (odd) -> conflict-free

typedef __attribute__((ext_vector_type(4))) float f32x4;
typedef __attribute__((ext_vector_type(4))) int i32x4;

__global__ void zero_kernel(int* __restrict__ p, int n) {
  int i = blockIdx.x * blockDim.x + threadIdx.x;
  if (i < n) p[i] = 0;
}

__device__ __forceinline__ void decode_point(const int* cp, bool& valid, int& idx) {
  int x = cp[0], y = cp[1], z = cp[2];
  valid = (x < DDIM) && (y < HDIM) && (z < WDIM);  // reference: upper bound only
  int xi = min(max(x, 0), DDIM - 1);
  int yi = min(max(y, 0), HDIM - 1);
  int zi = min(max(z, 0), WDIM - 1);
  idx = (xi * HDIM + yi) * WDIM + zi;
}

// records[g*CAP + pos] = pid | zoff<<19 | invalid<<23   (pid < 2^19)
__global__ void scatter_kernel(const int* __restrict__ coords, int* __restrict__ counts,
                               int* __restrict__ records, int* __restrict__ ovf_count,
                               int* __restrict__ ovf_list, int B, int N) {
  int p = blockIdx.x * blockDim.x + threadIdx.x;
  if (p >= B * N) return;
  int b = p / N;
  bool valid; int idx;
  decode_point(coords + (size_t)p * 3, valid, idx);
  int g = b * GROUPS_PER_B + (idx >> 4);
  int pos = atomicAdd(&counts[g], 1);
  if (pos < CAP) {
    records[g * CAP + pos] = p | ((idx & 15) << 19) | (valid ? 0 : (1 << 23));
  } else {
    int o = atomicAdd(ovf_count, 1);   // astronomically rare; correctness net
    ovf_list[o] = p;
  }
}

// One workgroup per GRP consecutive (b, line-group)s.
__global__ __launch_bounds__(256) void gather4_kernel(
    const float* __restrict__ vf, const int* __restrict__ counts,
    const int* __restrict__ records, float* __restrict__ out) {
  __shared__ float lds[CCH * ROWLEN];      // 37120 B
  __shared__ int s_rec[GRP * CAP];         // 1 KB
  __shared__ int s_cnt[GRP];
  int g0 = blockIdx.x * GRP;               // GRP divides GROUPS_PER_B: never straddles b
  int b = g0 >> NGROUPS_SHIFT;
  int group0 = g0 & (GROUPS_PER_B - 1);
  int t = threadIdx.x;

  // Prefetch records (1KB contiguous) + counts for all GRP groups.
  if (t < 64) {
    ((i32x4*)s_rec)[t] = ((const i32x4*)(records + (size_t)g0 * CAP))[t];
  }
  if (t < GRP) s_cnt[t] = counts[g0 + t];

  // Stage GRP*4KB: 64 channels x (GRP*16) floats, 512B contiguous per channel.
  {
    int ch = t >> 2;
    int sub = t & 3;
    const float* src = vf + ((size_t)(b * CCH + ch) << 18) + ((size_t)group0 << 4) + (sub << 2);
    float* dst = &lds[ch * ROWLEN + (sub << 2)];
#pragma unroll
    for (int i = 0; i < GRP; i++) {
      f32x4 v4 = __builtin_nontemporal_load((const f32x4*)(src + i * 16));
      dst[i * 16 + 0] = v4.x; dst[i * 16 + 1] = v4.y;
      dst[i * 16 + 2] = v4.z; dst[i * 16 + 3] = v4.w;
    }
  }
  __syncthreads();

  int ch = t & 63;
  int wv = t >> 6;                         // 4 waves split each group's points
#pragma unroll
  for (int i = 0; i < GRP; i++) {
    int cnt = min(s_cnt[i], CAP);
    for (int s = wv; s < cnt; s += 4) {
      int r = s_rec[i * CAP + s];          // LDS broadcast
      int pid = r & 0x7FFFF;
      int zoff = (r >> 19) & 15;
      float v = (r & (1 << 23)) ? 0.0f : lds[ch * ROWLEN + i * 16 + zoff];
      __builtin_nontemporal_store(v, &out[((size_t)pid << 6) + ch]);  // 256B coalesced
    }
  }
}

// Cleanup for bucket-overflow points (normally n==0: load one int, exit).
__global__ __launch_bounds__(256) void ovf_kernel(
    const float* __restrict__ vf, const int* __restrict__ coords,
    const int* __restrict__ ovf_count, const int* __restrict__ ovf_list,
    float* __restrict__ out, int N) {
  int n = *ovf_count;
  if (n == 0) return;
  int w = (blockIdx.x * blockDim.x + threadIdx.x) >> 6;
  int lane = threadIdx.x & 63;
  int nw = (gridDim.x * blockDim.x) >> 6;
  for (int i = w; i < n; i += nw) {
    int p = ovf_list[i];
    int b = p / N;
    bool valid; int idx;
    decode_point(coords + (size_t)p * 3, valid, idx);
    float v = valid ? vf[((size_t)(b * CCH + lane) << 18) + idx] : 0.0f;
    out[((size_t)p << 6) + lane] = v;
  }
}

// Fallback if workspace too small.
__global__ __launch_bounds__(256) void direct_kernel(const float* __restrict__ vf,
                                                     const int* __restrict__ coords,
                                                     float* __restrict__ out,
                                                     int B, int N) {
  int gid = blockIdx.x * blockDim.x + threadIdx.x;
  int point = gid >> 6;
  int lane = gid & 63;
  if (point >= B * N) return;
  int b = point / N;
  bool valid; int idx;
  decode_point(coords + (size_t)point * 3, valid, idx);
  float v = 0.0f;
  if (valid) v = vf[(size_t)(b * CCH + lane) * DHW + idx];
  out[(size_t)point * CCH + lane] = v;
}

extern "C" void kernel_launch(void* const* d_in, const int* in_sizes, int n_in,
                              void* d_out, int out_size, void* d_ws, size_t ws_size,
                              hipStream_t stream) {
  const float* vf = (const float*)d_in[0];
  const int* coords = (const int*)d_in[1];
  float* out = (float*)d_out;

  int B = in_sizes[0] / (CCH * DHW);  // 4
  int N = in_sizes[1] / (B * 3);      // 100000
  int total = B * N;

  int nbuckets = B * GROUPS_PER_B;                    // 65536
  size_t counts_ints = (size_t)nbuckets + 64;         // counts + ovf counter pad
  size_t rec_ints = (size_t)nbuckets * CAP;           // 2M ints = 8 MB
  size_t need = (counts_ints + rec_ints + (size_t)total) * sizeof(int);  // ~10.3 MB

  if (ws_size < need || total >= (1 << 19)) {
    int threads = total * 64;
    direct_kernel<<<(threads + 255) / 256, 256, 0, stream>>>(vf, coords, out, B, N);
    return;
  }

  int* counts = (int*)d_ws;
  int* ovf_count = counts + nbuckets;
  int* records = counts + counts_ints;
  int* ovf_list = records + rec_ints;

  zero_kernel<<<((int)counts_ints + 255) / 256, 256, 0, stream>>>(counts, (int)counts_ints);
  scatter_kernel<<<(total + 255) / 256, 256, 0, stream>>>(coords, counts, records,
                                                          ovf_count, ovf_list, B, N);
  gather4_kernel<<<nbuckets / GRP, 256, 0, stream>>>(vf, counts, records, out);
  ovf_kernel<<<32, 256, 0, stream>>>(vf, coords, ovf_count, ovf_list, out, N);
}